// Round 1
// baseline (959.195 us; speedup 1.0000x reference)
//
#include <hip/hip_runtime.h>
#include <math.h>

#define T_STEPS 1024
#define BATCH   32
#define DIM     1024
#define NST     64

// ======================= Phase 1: projection GEMMs =======================
// out[m][n] = sum_d x[m][d] * W[n][d], M = T*B = 32768, N = 64 (per W), K = 1024
// fp32 vector-ALU GEMM (no fp32 MFMA on CDNA4). Tile: 128(M) x 64(N) x 32(K),
// 256 threads, 32 outputs/thread (8x4).

#define MT 128
#define NT 64
#define KT 32

__global__ __launch_bounds__(256)
void proj_gemm_kernel(const float* __restrict__ x,
                      const float* __restrict__ Wk,
                      const float* __restrict__ Wv,
                      const float* __restrict__ Wq,
                      const float* __restrict__ Wa,
                      float* __restrict__ ws)
{
    // +1 pad => bank = (k + m) % 32: staging writes 2-way (free), compute reads broadcast
    __shared__ float As[KT][MT + 1];
    __shared__ float Bs[KT][NT + 1];

    const int tid  = threadIdx.x;
    const int wsel = blockIdx.y;
    const float* W = (wsel == 0) ? Wk : (wsel == 1) ? Wv : (wsel == 2) ? Wq : Wa;
    float* outb = ws + (size_t)wsel * ((size_t)T_STEPS * BATCH * NST);

    const int m0 = blockIdx.x * MT;

    const int lm = tid >> 3;        // 0..31  (row within staging pass)
    const int lk = (tid & 7) * 4;   // 0,4,...,28 (k offset, float4)

    const int tm = (tid >> 4) * 8;  // thread's 8 rows: tm..tm+7
    const int tn = (tid & 15) * 4;  // thread's 4 cols: tn..tn+3

    float acc[8][4];
    #pragma unroll
    for (int i = 0; i < 8; i++)
        #pragma unroll
        for (int j = 0; j < 4; j++) acc[i][j] = 0.f;

    for (int k0 = 0; k0 < DIM; k0 += KT) {
        __syncthreads();
        // stage A tile (128x32), coalesced float4 global reads
        #pragma unroll
        for (int p = 0; p < 4; p++) {
            const int mm = p * 32 + lm;
            const float4 v = *(const float4*)(x + (size_t)(m0 + mm) * DIM + k0 + lk);
            As[lk + 0][mm] = v.x;
            As[lk + 1][mm] = v.y;
            As[lk + 2][mm] = v.z;
            As[lk + 3][mm] = v.w;
        }
        // stage B tile (64x32)
        #pragma unroll
        for (int p = 0; p < 2; p++) {
            const int nn = p * 32 + lm;
            const float4 v = *(const float4*)(W + (size_t)nn * DIM + k0 + lk);
            Bs[lk + 0][nn] = v.x;
            Bs[lk + 1][nn] = v.y;
            Bs[lk + 2][nn] = v.z;
            Bs[lk + 3][nn] = v.w;
        }
        __syncthreads();

        #pragma unroll
        for (int kk = 0; kk < KT; kk++) {
            float a[8], bq[4];
            #pragma unroll
            for (int i = 0; i < 8; i++) a[i] = As[kk][tm + i];
            #pragma unroll
            for (int j = 0; j < 4; j++) bq[j] = Bs[kk][tn + j];
            #pragma unroll
            for (int i = 0; i < 8; i++)
                #pragma unroll
                for (int j = 0; j < 4; j++)
                    acc[i][j] += a[i] * bq[j];
        }
    }

    #pragma unroll
    for (int i = 0; i < 8; i++) {
        float4 o = make_float4(acc[i][0], acc[i][1], acc[i][2], acc[i][3]);
        *(float4*)(outb + (size_t)(m0 + tm + i) * NST + tn) = o;
    }
}

// ======================= Phase 2: sequential scan =======================
// Rows of S evolve independently given k_t (uniform per batch):
//   retrieved_i = S[i,:]·k ; alpha_i = sigmoid(ax_i + da_i*retr + ba_i)
//   S[i,:] = alpha_i*S[i,:] + (1-alpha_i)*v_i*k[:] ; h_i = S[i,:]·q ; out = h^2*sigmoid(h)
// Map: 4 lanes per row, 16 cols/lane, S in registers. One wave (64 lanes) = 16 rows.
// Grid = 32 batches x 4 row-quarters = 128 blocks x 64 threads.
// Cross-lane reduce over the quad via DPP quad_perm (VALU, no LDS).

__device__ __forceinline__ float dpp_xor1_add(float v) {
    // quad_perm [1,0,3,2] = 0xB1
    int o = __builtin_amdgcn_mov_dpp(__float_as_int(v), 0xB1, 0xF, 0xF, true);
    return v + __int_as_float(o);
}
__device__ __forceinline__ float dpp_xor2_add(float v) {
    // quad_perm [2,3,0,1] = 0x4E
    int o = __builtin_amdgcn_mov_dpp(__float_as_int(v), 0x4E, 0xF, 0xF, true);
    return v + __int_as_float(o);
}

__global__ __launch_bounds__(64)
void scan_kernel(const float* __restrict__ ws,
                 const float* __restrict__ S0,
                 const float* __restrict__ d_alpha,
                 const float* __restrict__ b_alpha,
                 float* __restrict__ out)
{
    const size_t TBN = (size_t)T_STEPS * BATCH * NST;
    const float* kb = ws;
    const float* vb = ws + TBN;
    const float* qb = ws + 2 * TBN;
    const float* ab = ws + 3 * TBN;

    const int lane = threadIdx.x;     // 0..63
    const int b    = blockIdx.x >> 2; // batch
    const int rq   = blockIdx.x & 3;  // row quarter
    const int rl   = lane >> 2;       // 0..15
    const int cg   = lane & 3;        // column group within quad
    const int row  = rq * 16 + rl;    // 0..63
    const int c0   = cg * 16;

    float S[16];
    {
        const float* s0p = S0 + ((size_t)b * NST + row) * NST + c0;
        #pragma unroll
        for (int j = 0; j < 4; j++) {
            float4 v = *(const float4*)(s0p + j * 4);
            S[j*4+0] = v.x; S[j*4+1] = v.y; S[j*4+2] = v.z; S[j*4+3] = v.w;
        }
    }
    const float da = d_alpha[row];
    const float ba = b_alpha[row];

    const size_t stp = (size_t)BATCH * NST;  // 2048
    const float* kp = kb + (size_t)b * NST + c0;
    const float* qp = qb + (size_t)b * NST + c0;
    const float* vp = vb + (size_t)b * NST + row;
    const float* ap = ab + (size_t)b * NST + row;
    float* op = out + (size_t)b * NST + row;

    float kA[16], qA[16], vA, axA;
    float kB[16], qB[16], vB, axB;

    auto loadStep = [&](int t, float* kf, float* qf, float& vv, float& aa) {
        const size_t off = (size_t)t * stp;
        #pragma unroll
        for (int j = 0; j < 4; j++) {
            float4 x4 = *(const float4*)(kp + off + j * 4);
            kf[j*4+0] = x4.x; kf[j*4+1] = x4.y; kf[j*4+2] = x4.z; kf[j*4+3] = x4.w;
        }
        #pragma unroll
        for (int j = 0; j < 4; j++) {
            float4 x4 = *(const float4*)(qp + off + j * 4);
            qf[j*4+0] = x4.x; qf[j*4+1] = x4.y; qf[j*4+2] = x4.z; qf[j*4+3] = x4.w;
        }
        vv = vp[off];
        aa = ap[off];
    };

    auto compute = [&](int t, const float* kf, const float* qf, float vv, float aa) {
        // retrieved = S·k  (4 independent accumulator chains)
        float p0 = 0.f, p1 = 0.f, p2 = 0.f, p3 = 0.f;
        #pragma unroll
        for (int j = 0; j < 4; j++) {
            p0 += S[j*4+0] * kf[j*4+0];
            p1 += S[j*4+1] * kf[j*4+1];
            p2 += S[j*4+2] * kf[j*4+2];
            p3 += S[j*4+3] * kf[j*4+3];
        }
        float part = (p0 + p1) + (p2 + p3);
        part = dpp_xor1_add(part);
        part = dpp_xor2_add(part);   // all 4 lanes of the quad have full retrieved_i

        const float z     = aa + da * part + ba;
        const float alpha = 1.f / (1.f + __expf(-z));
        const float w     = (1.f - alpha) * vv;

        #pragma unroll
        for (int j = 0; j < 16; j++)
            S[j] = alpha * S[j] + w * kf[j];

        float h0 = 0.f, h1 = 0.f, h2 = 0.f, h3 = 0.f;
        #pragma unroll
        for (int j = 0; j < 4; j++) {
            h0 += S[j*4+0] * qf[j*4+0];
            h1 += S[j*4+1] * qf[j*4+1];
            h2 += S[j*4+2] * qf[j*4+2];
            h3 += S[j*4+3] * qf[j*4+3];
        }
        float h = (h0 + h1) + (h2 + h3);
        h = dpp_xor1_add(h);
        h = dpp_xor2_add(h);

        const float sg = 1.f / (1.f + __expf(-h));
        const float o  = h * h * sg;     // h * silu(h)
        if (cg == 0) op[(size_t)t * stp] = o;
    };

    // software pipeline: loads of step t+1 issue before compute of step t
    loadStep(0, kA, qA, vA, axA);
    for (int t = 0; t < T_STEPS; t += 2) {
        loadStep(t + 1, kB, qB, vB, axB);
        compute(t, kA, qA, vA, axA);
        if (t + 2 < T_STEPS) loadStep(t + 2, kA, qA, vA, axA);
        compute(t + 1, kB, qB, vB, axB);
    }

    // S_final, concatenated after output in d_out
    float* sfp = out + TBN + ((size_t)b * NST + row) * NST + c0;
    #pragma unroll
    for (int j = 0; j < 4; j++)
        *(float4*)(sfp + j * 4) = make_float4(S[j*4+0], S[j*4+1], S[j*4+2], S[j*4+3]);
}

// ======================= launch =======================

extern "C" void kernel_launch(void* const* d_in, const int* in_sizes, int n_in,
                              void* d_out, int out_size, void* d_ws, size_t ws_size,
                              hipStream_t stream)
{
    const float* x  = (const float*)d_in[0];
    const float* S0 = (const float*)d_in[1];
    const float* Wk = (const float*)d_in[2];
    const float* Wv = (const float*)d_in[3];
    const float* Wq = (const float*)d_in[4];
    const float* Wa = (const float*)d_in[5];
    const float* da = (const float*)d_in[6];
    const float* ba = (const float*)d_in[7];
    float* out = (float*)d_out;
    float* ws  = (float*)d_ws;   // 4 x [T,B,N] fp32 = 32 MiB

    dim3 gemm_grid((T_STEPS * BATCH) / MT, 4);
    proj_gemm_kernel<<<gemm_grid, 256, 0, stream>>>(x, Wk, Wv, Wq, Wa, ws);

    scan_kernel<<<dim3(BATCH * 4), 64, 0, stream>>>(ws, S0, da, ba, out);
}

// Round 2
// 602.062 us; speedup vs baseline: 1.5932x; 1.5932x over previous
//
#include <hip/hip_runtime.h>
#include <math.h>

#define T_STEPS 1024
#define BATCH   32
#define DIM     1024
#define NST     64
#define TBN     ((size_t)T_STEPS * BATCH * NST)   // 2 M elements per projection

// ======================= Phase 1: fused projection GEMM =======================
// One GEMM: out[m][nf] = sum_d x[m][d] * Wf[nf][d], M=32768, Nf=256 (Wk|Wv|Wq|Wa), K=1024.
// fp32 vector ALU (no fp32 MFMA). Tile 128(M) x 128(N) x 32(K), 256 threads,
// per-thread 8x8 outputs => 64 FMA per 4 ds_read_b128 (2x better FMA:LDS than 8x4).
// Grid (256, 2): 512 blocks = 2 blocks/CU for barrier overlap.

#define MT 128
#define NT 128
#define KT 32

__global__ __launch_bounds__(256, 2)
void proj_gemm_fused(const float* __restrict__ x,
                     const float* __restrict__ Wk,
                     const float* __restrict__ Wv,
                     const float* __restrict__ Wq,
                     const float* __restrict__ Wa,
                     float* __restrict__ ws)
{
    __shared__ float As[KT][MT + 4];   // +4 keeps float4 alignment for b128 reads
    __shared__ float Bs[KT][NT + 4];

    const int tid = threadIdx.x;
    const int m0  = blockIdx.x * MT;
    const int nb0 = blockIdx.y * NT;   // 0 or 128 in fused-N space

    // staging ids: 8 lanes cover one row's 32 k-floats (128B segments, coalesced)
    const int lm = tid >> 3;          // 0..31
    const int lk = (tid & 7) * 4;     // 0,4,...,28

    // compute ids
    const int tm = (tid >> 4) * 8;    // 8 rows
    const int tn = (tid & 15) * 8;    // 8 cols (within 128-tile)

    // Precompute the 4 global row pointers for A and B staging
    const float* arow[4];
    const float* brow[4];
    #pragma unroll
    for (int p = 0; p < 4; p++) {
        arow[p] = x + (size_t)(m0 + p * 32 + lm) * DIM + lk;
        const int ng = nb0 + p * 32 + lm;               // fused col 0..255
        const float* W = (ng < 64) ? Wk : (ng < 128) ? Wv : (ng < 192) ? Wq : Wa;
        brow[p] = W + (size_t)(ng & 63) * DIM + lk;
    }

    float acc[8][8];
    #pragma unroll
    for (int i = 0; i < 8; i++)
        #pragma unroll
        for (int j = 0; j < 8; j++) acc[i][j] = 0.f;

    for (int k0 = 0; k0 < DIM; k0 += KT) {
        __syncthreads();
        #pragma unroll
        for (int p = 0; p < 4; p++) {
            const int mm = p * 32 + lm;
            const float4 v = *(const float4*)(arow[p] + k0);
            As[lk + 0][mm] = v.x; As[lk + 1][mm] = v.y;
            As[lk + 2][mm] = v.z; As[lk + 3][mm] = v.w;
        }
        #pragma unroll
        for (int p = 0; p < 4; p++) {
            const int nn = p * 32 + lm;
            const float4 v = *(const float4*)(brow[p] + k0);
            Bs[lk + 0][nn] = v.x; Bs[lk + 1][nn] = v.y;
            Bs[lk + 2][nn] = v.z; Bs[lk + 3][nn] = v.w;
        }
        __syncthreads();

        #pragma unroll 4
        for (int kk = 0; kk < KT; kk++) {
            float a[8], b[8];
            *(float4*)&a[0] = *(const float4*)&As[kk][tm];
            *(float4*)&a[4] = *(const float4*)&As[kk][tm + 4];
            *(float4*)&b[0] = *(const float4*)&Bs[kk][tn];
            *(float4*)&b[4] = *(const float4*)&Bs[kk][tn + 4];
            #pragma unroll
            for (int i = 0; i < 8; i++)
                #pragma unroll
                for (int j = 0; j < 8; j++)
                    acc[i][j] = fmaf(a[i], b[j], acc[i][j]);
        }
    }

    // epilogue: scatter into the 4 per-projection [T*B, 64] buffers
    const int ng0  = nb0 + tn;          // fused col of j=0 (mult of 8, no 64-crossing)
    const int wsel = ng0 >> 6;
    const int nloc = ng0 & 63;
    float* ob = ws + (size_t)wsel * TBN + nloc;
    #pragma unroll
    for (int i = 0; i < 8; i++) {
        float* o = ob + (size_t)(m0 + tm + i) * NST;
        *(float4*)(o)     = make_float4(acc[i][0], acc[i][1], acc[i][2], acc[i][3]);
        *(float4*)(o + 4) = make_float4(acc[i][4], acc[i][5], acc[i][6], acc[i][7]);
    }
}

// ======================= Phase 2: sequential scan =======================
// 8 lanes per state-row, 8 cols/lane; wave = 8 rows; grid = 32 b x 8 rowgroups = 256 blocks.
// S entirely in registers (8 VGPR/lane). Depth-4 register prefetch pipeline covers
// global-load latency. Cross-lane reduce over 8 lanes: quad_perm xor1, xor2, then
// row_half_mirror (all DPP/VALU, no LDS round-trip).

__device__ __forceinline__ float dpp_add_xor1(float v) {   // quad_perm [1,0,3,2]
    int o = __builtin_amdgcn_mov_dpp(__float_as_int(v), 0xB1, 0xF, 0xF, true);
    return v + __int_as_float(o);
}
__device__ __forceinline__ float dpp_add_xor2(float v) {   // quad_perm [2,3,0,1]
    int o = __builtin_amdgcn_mov_dpp(__float_as_int(v), 0x4E, 0xF, 0xF, true);
    return v + __int_as_float(o);
}
__device__ __forceinline__ float dpp_add_half_mirror(float v) { // ROW_HALF_MIRROR
    int o = __builtin_amdgcn_mov_dpp(__float_as_int(v), 0x141, 0xF, 0xF, true);
    return v + __int_as_float(o);
}

__device__ __forceinline__ float fast_sigmoid(float z) {
    // 1/(1+exp(-z)) via v_exp_f32 + v_rcp_f32
    float e = __builtin_amdgcn_exp2f(z * -1.44269504088896340736f);
    return __builtin_amdgcn_rcpf(1.0f + e);
}

__global__ __launch_bounds__(64)
void scan8_kernel(const float* __restrict__ ws,
                  const float* __restrict__ S0,
                  const float* __restrict__ d_alpha,
                  const float* __restrict__ b_alpha,
                  float* __restrict__ out)
{
    const float* kb = ws;
    const float* vb = ws + TBN;
    const float* qb = ws + 2 * TBN;
    const float* ab = ws + 3 * TBN;

    const int lane = threadIdx.x;      // 0..63
    const int b    = blockIdx.x >> 3;  // batch
    const int rg   = blockIdx.x & 7;   // row group (8 rows each)
    const int rl   = lane >> 3;        // 0..7 row within group
    const int cg   = lane & 7;         // 8-lane column group
    const int row  = rg * 8 + rl;      // 0..63
    const int c0   = cg * 8;

    float S[8];
    {
        const float* s0p = S0 + ((size_t)b * NST + row) * NST + c0;
        float4 v0 = *(const float4*)(s0p);
        float4 v1 = *(const float4*)(s0p + 4);
        S[0]=v0.x; S[1]=v0.y; S[2]=v0.z; S[3]=v0.w;
        S[4]=v1.x; S[5]=v1.y; S[6]=v1.z; S[7]=v1.w;
    }
    const float da = d_alpha[row];
    const float ba = b_alpha[row];

    const size_t stp = (size_t)BATCH * NST;   // 2048
    const float* kp = kb + (size_t)b * NST + c0;
    const float* qp = qb + (size_t)b * NST + c0;
    const float* vp = vb + (size_t)b * NST + row;
    const float* ap = ab + (size_t)b * NST + row;
    float* op = out + (size_t)b * NST + row;

    float kS[4][8], qS[4][8], vS[4], aS[4];

    auto loadStep = [&](int t, float* kf, float* qf, float& vv, float& aa) {
        const size_t off = (size_t)t * stp;
        float4 x0 = *(const float4*)(kp + off);
        float4 x1 = *(const float4*)(kp + off + 4);
        kf[0]=x0.x; kf[1]=x0.y; kf[2]=x0.z; kf[3]=x0.w;
        kf[4]=x1.x; kf[5]=x1.y; kf[6]=x1.z; kf[7]=x1.w;
        float4 y0 = *(const float4*)(qp + off);
        float4 y1 = *(const float4*)(qp + off + 4);
        qf[0]=y0.x; qf[1]=y0.y; qf[2]=y0.z; qf[3]=y0.w;
        qf[4]=y1.x; qf[5]=y1.y; qf[6]=y1.z; qf[7]=y1.w;
        vv = vp[off];
        aa = ap[off];
    };

    auto compute = [&](int t, const float* kf, const float* qf, float vv, float aa) {
        // retrieved = S.k : two 4-deep FMA chains + 3-stage DPP reduce
        float p0 = S[0] * kf[0];
        float p1 = S[1] * kf[1];
        p0 = fmaf(S[2], kf[2], p0);  p1 = fmaf(S[3], kf[3], p1);
        p0 = fmaf(S[4], kf[4], p0);  p1 = fmaf(S[5], kf[5], p1);
        p0 = fmaf(S[6], kf[6], p0);  p1 = fmaf(S[7], kf[7], p1);
        float part = p0 + p1;
        part = dpp_add_xor1(part);
        part = dpp_add_xor2(part);
        part = dpp_add_half_mirror(part);   // all 8 lanes hold retrieved_row

        const float z     = fmaf(da, part, aa + ba);
        const float alpha = fast_sigmoid(z);
        const float w     = (1.f - alpha) * vv;

        #pragma unroll
        for (int j = 0; j < 8; j++)
            S[j] = fmaf(alpha, S[j], w * kf[j]);

        float h0 = S[0] * qf[0];
        float h1 = S[1] * qf[1];
        h0 = fmaf(S[2], qf[2], h0);  h1 = fmaf(S[3], qf[3], h1);
        h0 = fmaf(S[4], qf[4], h0);  h1 = fmaf(S[5], qf[5], h1);
        h0 = fmaf(S[6], qf[6], h0);  h1 = fmaf(S[7], qf[7], h1);
        float h = h0 + h1;
        h = dpp_add_xor1(h);
        h = dpp_add_xor2(h);
        h = dpp_add_half_mirror(h);

        const float o = h * h * fast_sigmoid(h);   // h * silu(h)
        if (cg == 0) op[(size_t)t * stp] = o;
    };

    // depth-4 software pipeline (loads issue 3 steps ahead of use)
    loadStep(0, kS[0], qS[0], vS[0], aS[0]);
    loadStep(1, kS[1], qS[1], vS[1], aS[1]);
    loadStep(2, kS[2], qS[2], vS[2], aS[2]);

    for (int t = 0; t < T_STEPS; t += 4) {
        int t3 = t + 3 < T_STEPS ? t + 3 : T_STEPS - 1;
        int t4 = t + 4 < T_STEPS ? t + 4 : T_STEPS - 1;
        int t5 = t + 5 < T_STEPS ? t + 5 : T_STEPS - 1;
        int t6 = t + 6 < T_STEPS ? t + 6 : T_STEPS - 1;
        loadStep(t3, kS[3], qS[3], vS[3], aS[3]);
        compute(t + 0, kS[0], qS[0], vS[0], aS[0]);
        loadStep(t4, kS[0], qS[0], vS[0], aS[0]);
        compute(t + 1, kS[1], qS[1], vS[1], aS[1]);
        loadStep(t5, kS[1], qS[1], vS[1], aS[1]);
        compute(t + 2, kS[2], qS[2], vS[2], aS[2]);
        loadStep(t6, kS[2], qS[2], vS[2], aS[2]);
        compute(t + 3, kS[3], qS[3], vS[3], aS[3]);
    }

    // S_final, concatenated after output
    float* sfp = out + TBN + ((size_t)b * NST + row) * NST + c0;
    *(float4*)(sfp)     = make_float4(S[0], S[1], S[2], S[3]);
    *(float4*)(sfp + 4) = make_float4(S[4], S[5], S[6], S[7]);
}

// ======================= launch =======================

extern "C" void kernel_launch(void* const* d_in, const int* in_sizes, int n_in,
                              void* d_out, int out_size, void* d_ws, size_t ws_size,
                              hipStream_t stream)
{
    const float* x  = (const float*)d_in[0];
    const float* S0 = (const float*)d_in[1];
    const float* Wk = (const float*)d_in[2];
    const float* Wv = (const float*)d_in[3];
    const float* Wq = (const float*)d_in[4];
    const float* Wa = (const float*)d_in[5];
    const float* da = (const float*)d_in[6];
    const float* ba = (const float*)d_in[7];
    float* out = (float*)d_out;
    float* ws  = (float*)d_ws;   // 4 x [T,B,N] fp32 = 32 MiB

    dim3 gemm_grid((T_STEPS * BATCH) / MT, 2);
    proj_gemm_fused<<<gemm_grid, 256, 0, stream>>>(x, Wk, Wv, Wq, Wa, ws);

    scan8_kernel<<<dim3(BATCH * 8), 64, 0, stream>>>(ws, S0, da, ba, out);
}